// Round 8
// baseline (1216.306 us; speedup 1.0000x reference)
//
#include <hip/hip_runtime.h>
#include <stddef.h>
#include <stdint.h>

#define N_NODES 50000
#define N_EDGES 800000
#define NF 96
#define FE 64
#define DIN 256
#define DOUT 192
#define BN_EPS 1e-5f
#define NTILES (N_EDGES / 64)

// LDS region layout (shorts): As1[64][104] | As2[64][104] | Ase[64][72]
#define R1_STRIDE 104
#define R2_BASE 6656
#define RE_BASE 13312
#define RE_STRIDE 72
#define LDS_SHORTS 17920
#define NCHUNK 2048  // 64*(12+12+8) 16B chunks per tile

typedef float f32x4 __attribute__((ext_vector_type(4)));
typedef short bf16x8 __attribute__((ext_vector_type(8)));

__device__ __forceinline__ unsigned short f2bf(float f) {
  unsigned int u = __float_as_uint(f);
  return (unsigned short)((u + 0x7fffu + ((u >> 16) & 1u)) >> 16);
}
__device__ __forceinline__ float sigmoidf_(float x) {
  return 1.f / (1.f + __expf(-x));
}
// softplus via exp2f/log2f -> v_exp_f32 / v_log_f32
__device__ __forceinline__ float softplusf_(float x) {
  float t = exp2f(-fabsf(x) * 1.44269504f);
  return fmaxf(x, 0.f) + 0.69314718f * log2f(1.f + t);
}

// row permutation: A-row r holds edge e0 + rperm_(r); swaps rf<->hi so a
// thread's 16 C-fragment values are 16 CONSECUTIVE edges (hi*16 + rf*4 + j).
// (named rperm_ because EPERM collides with the errno.h macro)
__device__ __forceinline__ int rperm_(int r) {
  return ((r >> 2) & 3) * 16 + (r >> 4) * 4 + (r & 3);
}

// our col c' = t*16+lm -> orig col: t even -> gate (t/2)*16+lm ; t odd -> conv 96+(t/2)*16+lm
__device__ __forceinline__ int col_perm(int c) {
  int t = c >> 4, lm = c & 15;
  return (t >> 1) * 16 + (t & 1) * 96 + lm;
}

// ---------------- conversion / sort kernels ----------------
__global__ void k_cvt(const float* __restrict__ in, unsigned short* __restrict__ out, int n4) {
  int stride = gridDim.x * blockDim.x;
  for (int i = blockIdx.x * blockDim.x + threadIdx.x; i < n4; i += stride) {
    float4 v = reinterpret_cast<const float4*>(in)[i];
    ushort4 o;
    o.x = f2bf(v.x); o.y = f2bf(v.y); o.z = f2bf(v.z); o.w = f2bf(v.w);
    reinterpret_cast<ushort4*>(out)[i] = o;
  }
}

__global__ void k_cvt_w(const float* __restrict__ W, unsigned short* __restrict__ Wt) {
  int i = blockIdx.x * blockDim.x + threadIdx.x;
  if (i < DOUT * DIN) {
    int c = i / DIN, k = i % DIN;
    Wt[i] = f2bf(W[k * DOUT + col_perm(c)]);
  }
}

__global__ void k_hist(const int* __restrict__ idx1, int* __restrict__ icounts) {
  int stride = gridDim.x * blockDim.x;
  for (int e = blockIdx.x * blockDim.x + threadIdx.x; e < N_EDGES; e += stride)
    atomicAdd(&icounts[idx1[e]], 1);
}

// ---- 3-phase multi-block exclusive scan of icounts[50000] -> offsets ----
#define SCAN_B 512
#define SCAN_NB 98
__global__ void k_scanA(const int* __restrict__ ic, int* __restrict__ off,
                        int* __restrict__ bsum) {
  __shared__ int tmp[SCAN_B];
  int tid = threadIdx.x, i = blockIdx.x * SCAN_B + tid;
  int v = (i < N_NODES) ? ic[i] : 0;
  tmp[tid] = v;
  __syncthreads();
  for (int o = 1; o < SCAN_B; o <<= 1) {
    int t = (tid >= o) ? tmp[tid - o] : 0;
    __syncthreads();
    tmp[tid] += t;
    __syncthreads();
  }
  if (i < N_NODES) off[i] = tmp[tid] - v;
  if (tid == SCAN_B - 1) bsum[blockIdx.x] = tmp[tid];
}
__global__ void k_scanB(const int* __restrict__ bsum, int* __restrict__ boff) {
  __shared__ int tmp[128];
  int tid = threadIdx.x;
  int v = (tid < SCAN_NB) ? bsum[tid] : 0;
  tmp[tid] = v;
  __syncthreads();
  for (int o = 1; o < 128; o <<= 1) {
    int t = (tid >= o) ? tmp[tid - o] : 0;
    __syncthreads();
    tmp[tid] += t;
    __syncthreads();
  }
  if (tid < SCAN_NB) boff[tid] = tmp[tid] - v;
}
__global__ void k_scanC(int* __restrict__ off, const int* __restrict__ boff) {
  int i = blockIdx.x * SCAN_B + threadIdx.x;
  if (i < N_NODES) off[i] += boff[blockIdx.x];
}

// scatter edge ids into sorted-by-idx1 order
__global__ void k_perm(const int* __restrict__ idx1, const int* __restrict__ offsets,
                       int* __restrict__ cursor, int* __restrict__ perm,
                       int* __restrict__ i1s) {
  int stride = gridDim.x * blockDim.x;
  for (int e = blockIdx.x * blockDim.x + threadIdx.x; e < N_EDGES; e += stride) {
    int n = idx1[e];
    int p = offsets[n] + atomicAdd(&cursor[n], 1);
    perm[p] = e;
    i1s[p] = n;
  }
}

// ---------------- shared GEMM machinery ----------------
#define GEMM_PROLOGUE()                                                          \
  const int tid = threadIdx.x;                                                   \
  const int lane = tid & 63;                                                     \
  const int w = tid >> 6;                                                        \
  const int lm = lane & 15;                                                      \
  const int hi = lane >> 4;                                                      \
  const int base_c = w * 32;                                                     \
  bf16x8 breg[2][8];                                                             \
  _Pragma("unroll") for (int ct = 0; ct < 2; ++ct)                               \
  _Pragma("unroll") for (int ks = 0; ks < 8; ++ks)                               \
      breg[ct][ks] = *reinterpret_cast<const bf16x8*>(                           \
          Wt + (size_t)(base_c + ct * 16 + lm) * DIN + ks * 32 + hi * 8);        \
  int dstv[6];                                                                   \
  _Pragma("unroll") for (int k = 0; k < 6; ++k) {                                \
    int i = tid + k * 384;                                                       \
    if (i < 768)       dstv[k] = (i / 12) * R1_STRIDE + (i % 12) * 8;            \
    else if (i < 1536) { int ii = i - 768;                                       \
                         dstv[k] = R2_BASE + (ii / 12) * R1_STRIDE + (ii % 12) * 8; } \
    else               { int ii = i - 1536;                                      \
                         dstv[k] = RE_BASE + (ii >> 3) * RE_STRIDE + (ii & 7) * 8; } \
  }                                                                              \
  uint4 sv[6];

#define WRITE_TILE()                                                             \
  _Pragma("unroll") for (int k = 0; k < 6; ++k) {                                \
    int i = tid + k * 384;                                                       \
    if (i < NCHUNK) *reinterpret_cast<uint4*>(&As[dstv[k]]) = sv[k];             \
  }

#define COMPUTE_TILE()                                                           \
  _Pragma("unroll") for (int ks = 0; ks < 8; ++ks) {                             \
    bf16x8 a[4];                                                                 \
    _Pragma("unroll") for (int rf = 0; rf < 4; ++rf) {                           \
      int row = rf * 16 + lm;                                                    \
      int off;                                                                   \
      if (ks < 3)      off = row * R1_STRIDE + (ks * 4 + hi) * 8;                \
      else if (ks < 6) off = R2_BASE + row * R1_STRIDE + ((ks - 3) * 4 + hi) * 8;\
      else             off = RE_BASE + row * RE_STRIDE + ((ks - 6) * 4 + hi) * 8;\
      a[rf] = *reinterpret_cast<const bf16x8*>(&As[off]);                        \
    }                                                                            \
    _Pragma("unroll") for (int rf = 0; rf < 4; ++rf)                             \
    _Pragma("unroll") for (int ct = 0; ct < 2; ++ct)                             \
        acc[rf][ct] = __builtin_amdgcn_mfma_f32_16x16x32_bf16(                   \
            a[rf], breg[ct][ks], acc[rf][ct], 0, 0, 0);                          \
  }

// PASS 0: column stats of y = XW, original edge order (rperm_ harmless)
__global__ __launch_bounds__(384, 6) void k_gstats(
    const unsigned short* __restrict__ nb, const unsigned short* __restrict__ eb,
    const unsigned short* __restrict__ Wt, const int* __restrict__ idx1,
    const int* __restrict__ idx2, float* __restrict__ colsum, float* __restrict__ colsumsq) {
  __shared__ unsigned short As[LDS_SHORTS];
  GEMM_PROLOGUE();
  float s1a[2] = {0.f, 0.f}, s2a[2] = {0.f, 0.f};

#define LOAD_TILE0(T)                                                            \
  {                                                                              \
    const int e0_ = (T) * 64;                                                    \
    _Pragma("unroll") for (int k = 0; k < 6; ++k) {                              \
      int i = tid + k * 384;                                                     \
      if (i < NCHUNK) {                                                          \
        const unsigned short* src;                                               \
        if (i < 768)       { int r = i / 12, c = i % 12;                         \
                             src = nb + (size_t)idx1[e0_ + rperm_(r)] * NF + c * 8; } \
        else if (i < 1536) { int ii = i - 768; int r = ii / 12, c = ii % 12;     \
                             src = nb + (size_t)idx2[e0_ + rperm_(r)] * NF + c * 8; } \
        else               { int ii = i - 1536; int r = ii >> 3, c = ii & 7;     \
                             src = eb + (size_t)(e0_ + rperm_(r)) * FE + c * 8; } \
        sv[k] = *reinterpret_cast<const uint4*>(src);                            \
      }                                                                          \
    }                                                                            \
  }

  int tile = blockIdx.x;
  if (tile < NTILES) LOAD_TILE0(tile);
  for (; tile < NTILES; tile += gridDim.x) {
    __syncthreads();
    WRITE_TILE();
    __syncthreads();
    int nt = tile + gridDim.x;
    if (nt < NTILES) LOAD_TILE0(nt);

    f32x4 acc[4][2];
#pragma unroll
    for (int rf = 0; rf < 4; ++rf)
#pragma unroll
      for (int ct = 0; ct < 2; ++ct) acc[rf][ct] = (f32x4)(0.f);
    COMPUTE_TILE();

#pragma unroll
    for (int ct = 0; ct < 2; ++ct)
#pragma unroll
      for (int rf = 0; rf < 4; ++rf)
#pragma unroll
        for (int j = 0; j < 4; ++j) {
          float y = acc[rf][ct][j];
          s1a[ct] += y;
          s2a[ct] += y * y;
        }
  }

#pragma unroll
  for (int ct = 0; ct < 2; ++ct) {
    float s1 = s1a[ct], s2 = s2a[ct];
    s1 += __shfl_xor(s1, 16); s2 += __shfl_xor(s2, 16);
    s1 += __shfl_xor(s1, 32); s2 += __shfl_xor(s2, 32);
    if (lane < 16) {
      atomicAdd(&colsum[base_c + ct * 16 + lane], s1);
      atomicAdd(&colsumsq[base_c + ct * 16 + lane], s2);
    }
  }
}

// PASS 1: sorted edges, row-permuted staging; in-register segmented scatter.
// Thread (hi) holds 16 consecutive sorted edges e0+hi*16+k for col mcol.
__global__ __launch_bounds__(384, 6) void k_gmsg2(
    const unsigned short* __restrict__ nb, const unsigned short* __restrict__ eb,
    const unsigned short* __restrict__ Wt, const int* __restrict__ perm,
    const int* __restrict__ i1s, const int* __restrict__ idx2,
    const float* __restrict__ a1, const float* __restrict__ b1f,
    float* __restrict__ sums) {
  __shared__ unsigned short As[LDS_SHORTS];
  __shared__ int nid[64];
  GEMM_PROLOGUE();
  float c0[2], c1[2];
#pragma unroll
  for (int ct = 0; ct < 2; ++ct) {
    c0[ct] = a1[base_c + ct * 16 + lm];
    c1[ct] = b1f[base_c + ct * 16 + lm];
  }

#define LOAD_TILE1(T)                                                            \
  {                                                                              \
    const int e0_ = (T) * 64;                                                    \
    _Pragma("unroll") for (int k = 0; k < 6; ++k) {                              \
      int i = tid + k * 384;                                                     \
      if (i < NCHUNK) {                                                          \
        const unsigned short* src;                                               \
        if (i < 768)       { int r = i / 12, c = i % 12;                         \
                             src = nb + (size_t)i1s[e0_ + rperm_(r)] * NF + c * 8; } \
        else if (i < 1536) { int ii = i - 768; int r = ii / 12, c = ii % 12;     \
                             int ep = perm[e0_ + rperm_(r)];                     \
                             src = nb + (size_t)idx2[ep] * NF + c * 8; }         \
        else               { int ii = i - 1536; int r = ii >> 3, c = ii & 7;     \
                             int ep = perm[e0_ + rperm_(r)];                     \
                             src = eb + (size_t)ep * FE + c * 8; }               \
        sv[k] = *reinterpret_cast<const uint4*>(src);                            \
      }                                                                          \
    }                                                                            \
  }

  int tile = blockIdx.x;
  if (tile < NTILES) LOAD_TILE1(tile);
  for (; tile < NTILES; tile += gridDim.x) {
    const int e0 = tile * 64;
    __syncthreads();  // (A) prev epilogue done (nid safe to overwrite)
    WRITE_TILE();
    if (tid < 64) nid[tid] = i1s[e0 + tid];
    __syncthreads();  // (B)
    int nt = tile + gridDim.x;
    if (nt < NTILES) LOAD_TILE1(nt);

    f32x4 acc[4][2];
#pragma unroll
    for (int rf = 0; rf < 4; ++rf)
#pragma unroll
      for (int ct = 0; ct < 2; ++ct) acc[rf][ct] = (f32x4)(0.f);
    COMPUTE_TILE();

    // in-register segmented scatter: edges e0+hi*16+0..15 in (rf,j) lex order
    const int mcol = w * 16 + lm;
    float run = 0.f;
    int curn = nid[hi * 16];
#pragma unroll
    for (int rf = 0; rf < 4; ++rf)
#pragma unroll
      for (int j = 0; j < 4; ++j) {
        int k = rf * 4 + j;
        float zg = acc[rf][0][j] * c0[0] + c1[0];
        float zc = acc[rf][1][j] * c0[1] + c1[1];
        run += sigmoidf_(zg) * softplusf_(zc);
        int nxt = (k < 15) ? nid[hi * 16 + k + 1] : -1;
        if (nxt != curn) {
          atomicAdd(&sums[(size_t)curn * NF + mcol], run);
          run = 0.f;
          curn = nxt;
        }
      }
  }
}

// ---------------- BN affine computation ----------------
__global__ void k_bn1(const float* __restrict__ colsum, const float* __restrict__ colsumsq,
                      const float* __restrict__ gamma1, const float* __restrict__ beta1,
                      float* __restrict__ a1, float* __restrict__ b1f) {
  int c = threadIdx.x;  // 192, our col space
  int o = col_perm(c);
  float my = colsum[c] * (1.f / N_EDGES);
  float v = colsumsq[c] * (1.f / N_EDGES) - my * my;
  float a = gamma1[o] * rsqrtf(v + BN_EPS);
  a1[c] = a;
  b1f[c] = beta1[o] - my * a;  // bias cancels against batch mean
}

__global__ void k_nodestats(const float* __restrict__ sums, const int* __restrict__ icounts,
                            float* __restrict__ colsum2, float* __restrict__ colsumsq2) {
  __shared__ float sh[2][2][96];
  int t = threadIdx.x;  // 192
  int c = t % 96, sub = t / 96;
  float s1 = 0.f, s2 = 0.f;
  int n0 = blockIdx.x * 256;
  for (int r = sub; r < 256; r += 2) {
    int n = n0 + r;
    if (n < N_NODES) {
      float v = sums[(size_t)n * NF + c] / fmaxf((float)icounts[n], 1.f);
      s1 += v; s2 += v * v;
    }
  }
  sh[0][sub][c] = s1; sh[1][sub][c] = s2;
  __syncthreads();
  if (sub == 0) {
    atomicAdd(&colsum2[c], s1 + sh[0][1][c]);
    atomicAdd(&colsumsq2[c], s2 + sh[1][1][c]);
  }
}

__global__ void k_bn2(const float* __restrict__ colsum2, const float* __restrict__ colsumsq2,
                      const float* __restrict__ gamma2, const float* __restrict__ beta2,
                      float* __restrict__ a2, float* __restrict__ b2f) {
  int c = threadIdx.x;
  if (c < 96) {
    float m = colsum2[c] * (1.f / N_NODES);
    float v = colsumsq2[c] * (1.f / N_NODES) - m * m;
    float a = gamma2[c] * rsqrtf(v + BN_EPS);
    a2[c] = a;
    b2f[c] = beta2[c] - m * a;
  }
}

__global__ void k_final(const float* __restrict__ node, const float* __restrict__ sums,
                        const int* __restrict__ icounts, const float* __restrict__ a2,
                        const float* __restrict__ b2f, float* __restrict__ out) {
  int stride = gridDim.x * blockDim.x;
  for (int i = blockIdx.x * blockDim.x + threadIdx.x; i < N_NODES * NF / 4; i += stride) {
    int n = i / 24, c4 = (i % 24) * 4;
    float inv = 1.f / fmaxf((float)icounts[n], 1.f);
    float4 s = reinterpret_cast<const float4*>(sums)[i];
    float4 nf = reinterpret_cast<const float4*>(node)[i];
    float4 o;
    o.x = softplusf_(nf.x + s.x * inv * a2[c4 + 0] + b2f[c4 + 0]);
    o.y = softplusf_(nf.y + s.y * inv * a2[c4 + 1] + b2f[c4 + 1]);
    o.z = softplusf_(nf.z + s.z * inv * a2[c4 + 2] + b2f[c4 + 2]);
    o.w = softplusf_(nf.w + s.w * inv * a2[c4 + 3] + b2f[c4 + 3]);
    reinterpret_cast<float4*>(out)[i] = o;
  }
}

extern "C" void kernel_launch(void* const* d_in, const int* in_sizes, int n_in,
                              void* d_out, int out_size, void* d_ws, size_t ws_size,
                              hipStream_t stream) {
  const float* node = (const float*)d_in[0];
  const float* edge = (const float*)d_in[1];
  const float* W = (const float*)d_in[2];
  const float* gamma1 = (const float*)d_in[4];
  const float* beta1 = (const float*)d_in[5];
  const float* gamma2 = (const float*)d_in[6];
  const float* beta2 = (const float*)d_in[7];
  const int* idx1 = (const int*)d_in[8];
  const int* idx2 = (const int*)d_in[9];
  float* out = (float*)d_out;

  char* ws = (char*)d_ws;
  unsigned short* nb = (unsigned short*)(ws);               //   9,600,000
  unsigned short* eb = (unsigned short*)(ws + 9600000);     // 102,400,000
  unsigned short* Wt = (unsigned short*)(ws + 112000000);   //      98,304
  float* sums = (float*)(ws + 112098304);                   //  19,200,000
  float* stats = (float*)(ws + 131298304);                  //       8,192
  int* icounts = (int*)(ws + 131306496);                    //     200,000
  int* perm = (int*)(ws + 131506496);                       //   3,200,000
  int* i1s = (int*)(ws + 134706496);                        //   3,200,000
  // total 137,906,496 bytes

  // overlay at head of sums (used only before k_gmsg2, re-zeroed after)
  int* offsets = (int*)(ws + 112098304);        // 50000 ints
  int* cursor = offsets + 50048;                // 50000 ints

  float* colsum1 = stats;          // 192
  float* colsumsq1 = stats + 192;  // 192
  float* colsum2 = stats + 384;    // 96
  float* colsumsq2 = stats + 480;  // 96
  float* a1 = stats + 576;         // 192
  float* b1f = stats + 768;        // 192
  float* a2 = stats + 960;         // 96
  float* b2f = stats + 1056;       // 96
  int* bsum = (int*)(ws + 131303424);  // 128 ints
  int* boff = (int*)(ws + 131303936);  // 128 ints

  // zero sums (incl. offsets/cursor overlay) + stats + icounts
  (void)hipMemsetAsync(ws + 112098304, 0, 19200000 + 8192 + 200000, stream);

  k_cvt<<<2048, 256, 0, stream>>>(node, nb, N_NODES * NF / 4);
  k_cvt<<<2048, 256, 0, stream>>>(edge, eb, N_EDGES * FE / 4);
  k_cvt_w<<<DOUT * DIN / 256, 256, 0, stream>>>(W, Wt);
  k_hist<<<1024, 256, 0, stream>>>(idx1, icounts);
  k_scanA<<<SCAN_NB, SCAN_B, 0, stream>>>(icounts, offsets, bsum);
  k_scanB<<<1, 128, 0, stream>>>(bsum, boff);
  k_scanC<<<SCAN_NB, SCAN_B, 0, stream>>>(offsets, boff);
  k_perm<<<1024, 256, 0, stream>>>(idx1, offsets, cursor, perm, i1s);

  k_gstats<<<1024, 384, 0, stream>>>(nb, eb, Wt, idx1, idx2, colsum1, colsumsq1);
  k_bn1<<<1, 192, 0, stream>>>(colsum1, colsumsq1, gamma1, beta1, a1, b1f);

  // re-zero the overlay region before atomic accumulation into sums
  (void)hipMemsetAsync(ws + 112098304, 0, 524288, stream);

  k_gmsg2<<<1024, 384, 0, stream>>>(nb, eb, Wt, perm, i1s, idx2, a1, b1f, sums);

  k_nodestats<<<(N_NODES + 255) / 256, 192, 0, stream>>>(sums, icounts, colsum2, colsumsq2);
  k_bn2<<<1, 128, 0, stream>>>(colsum2, colsumsq2, gamma2, beta2, a2, b2f);
  k_final<<<2048, 256, 0, stream>>>(node, sums, icounts, a2, b2f, out);
}

// Round 9
// 930.215 us; speedup vs baseline: 1.3076x; 1.3076x over previous
//
#include <hip/hip_runtime.h>
#include <stddef.h>
#include <stdint.h>

#define N_NODES 50000
#define N_EDGES 800000
#define NF 96
#define FE 64
#define DIN 256
#define DOUT 192
#define BN_EPS 1e-5f
#define NTILES (N_EDGES / 64)

// LDS region layout (shorts): As1[64][104] | As2[64][104] | Ase[64][72]
#define R1_STRIDE 104
#define R2_BASE 6656
#define RE_BASE 13312
#define RE_STRIDE 72
#define LDS_SHORTS 17920
#define NCHUNK 2048  // 64*(12+12+8) 16B chunks per tile

typedef float f32x4 __attribute__((ext_vector_type(4)));
typedef short bf16x8 __attribute__((ext_vector_type(8)));

__device__ __forceinline__ unsigned short f2bf(float f) {
  unsigned int u = __float_as_uint(f);
  return (unsigned short)((u + 0x7fffu + ((u >> 16) & 1u)) >> 16);
}
__device__ __forceinline__ float sigmoidf_(float x) {
  return 1.f / (1.f + __expf(-x));
}
// softplus via exp2f/log2f -> v_exp_f32 / v_log_f32
__device__ __forceinline__ float softplusf_(float x) {
  float t = exp2f(-fabsf(x) * 1.44269504f);
  return fmaxf(x, 0.f) + 0.69314718f * log2f(1.f + t);
}

// row permutation: A-row r holds edge e0 + rperm_(r); swaps rf<->hi so a
// thread's 16 C-fragment values are 16 CONSECUTIVE edges (hi*16 + rf*4 + j).
__device__ __forceinline__ int rperm_(int r) {
  return ((r >> 2) & 3) * 16 + (r >> 4) * 4 + (r & 3);
}

// our col c' = t*16+lm -> orig col: t even -> gate (t/2)*16+lm ; t odd -> conv 96+(t/2)*16+lm
__device__ __forceinline__ int col_perm(int c) {
  int t = c >> 4, lm = c & 15;
  return (t >> 1) * 16 + (t & 1) * 96 + lm;
}

// ---------------- conversion / sort kernels ----------------
__global__ void k_cvt(const float* __restrict__ in, unsigned short* __restrict__ out, int n4) {
  int stride = gridDim.x * blockDim.x;
  for (int i = blockIdx.x * blockDim.x + threadIdx.x; i < n4; i += stride) {
    float4 v = reinterpret_cast<const float4*>(in)[i];
    ushort4 o;
    o.x = f2bf(v.x); o.y = f2bf(v.y); o.z = f2bf(v.z); o.w = f2bf(v.w);
    reinterpret_cast<ushort4*>(out)[i] = o;
  }
}

__global__ void k_cvt_w(const float* __restrict__ W, unsigned short* __restrict__ Wt) {
  int i = blockIdx.x * blockDim.x + threadIdx.x;
  if (i < DOUT * DIN) {
    int c = i / DIN, k = i % DIN;
    Wt[i] = f2bf(W[k * DOUT + col_perm(c)]);
  }
}

__global__ void k_hist(const int* __restrict__ idx1, int* __restrict__ icounts) {
  int stride = gridDim.x * blockDim.x;
  for (int e = blockIdx.x * blockDim.x + threadIdx.x; e < N_EDGES; e += stride)
    atomicAdd(&icounts[idx1[e]], 1);
}

// ---- 3-phase multi-block exclusive scan of icounts[50000] -> offsets ----
#define SCAN_B 512
#define SCAN_NB 98
__global__ void k_scanA(const int* __restrict__ ic, int* __restrict__ off,
                        int* __restrict__ bsum) {
  __shared__ int tmp[SCAN_B];
  int tid = threadIdx.x, i = blockIdx.x * SCAN_B + tid;
  int v = (i < N_NODES) ? ic[i] : 0;
  tmp[tid] = v;
  __syncthreads();
  for (int o = 1; o < SCAN_B; o <<= 1) {
    int t = (tid >= o) ? tmp[tid - o] : 0;
    __syncthreads();
    tmp[tid] += t;
    __syncthreads();
  }
  if (i < N_NODES) off[i] = tmp[tid] - v;
  if (tid == SCAN_B - 1) bsum[blockIdx.x] = tmp[tid];
}
__global__ void k_scanB(const int* __restrict__ bsum, int* __restrict__ boff) {
  __shared__ int tmp[128];
  int tid = threadIdx.x;
  int v = (tid < SCAN_NB) ? bsum[tid] : 0;
  tmp[tid] = v;
  __syncthreads();
  for (int o = 1; o < 128; o <<= 1) {
    int t = (tid >= o) ? tmp[tid - o] : 0;
    __syncthreads();
    tmp[tid] += t;
    __syncthreads();
  }
  if (tid < SCAN_NB) boff[tid] = tmp[tid] - v;
}
__global__ void k_scanC(int* __restrict__ off, const int* __restrict__ boff) {
  int i = blockIdx.x * SCAN_B + threadIdx.x;
  if (i < N_NODES) off[i] += boff[blockIdx.x];
}

// scatter edge ids into sorted-by-idx1 order
__global__ void k_perm(const int* __restrict__ idx1, const int* __restrict__ offsets,
                       int* __restrict__ cursor, int* __restrict__ perm,
                       int* __restrict__ i1s) {
  int stride = gridDim.x * blockDim.x;
  for (int e = blockIdx.x * blockDim.x + threadIdx.x; e < N_EDGES; e += stride) {
    int n = idx1[e];
    int p = offsets[n] + atomicAdd(&cursor[n], 1);
    perm[p] = e;
    i1s[p] = n;
  }
}

// ---------------- shared GEMM machinery ----------------
#define GEMM_PROLOGUE()                                                          \
  const int tid = threadIdx.x;                                                   \
  const int lane = tid & 63;                                                     \
  const int w = tid >> 6;                                                        \
  const int lm = lane & 15;                                                      \
  const int hi = lane >> 4;                                                      \
  const int base_c = w * 32;                                                     \
  bf16x8 breg[2][8];                                                             \
  _Pragma("unroll") for (int ct = 0; ct < 2; ++ct)                               \
  _Pragma("unroll") for (int ks = 0; ks < 8; ++ks)                               \
      breg[ct][ks] = *reinterpret_cast<const bf16x8*>(                           \
          Wt + (size_t)(base_c + ct * 16 + lm) * DIN + ks * 32 + hi * 8);        \
  int dstv[6];                                                                   \
  _Pragma("unroll") for (int k = 0; k < 6; ++k) {                                \
    int i = tid + k * 384;                                                       \
    if (i < 768)       dstv[k] = (i / 12) * R1_STRIDE + (i % 12) * 8;            \
    else if (i < 1536) { int ii = i - 768;                                       \
                         dstv[k] = R2_BASE + (ii / 12) * R1_STRIDE + (ii % 12) * 8; } \
    else               { int ii = i - 1536;                                      \
                         dstv[k] = RE_BASE + (ii >> 3) * RE_STRIDE + (ii & 7) * 8; } \
  }                                                                              \
  uint4 sv[6];

#define WRITE_TILE()                                                             \
  _Pragma("unroll") for (int k = 0; k < 6; ++k) {                                \
    int i = tid + k * 384;                                                       \
    if (i < NCHUNK) *reinterpret_cast<uint4*>(&As[dstv[k]]) = sv[k];             \
  }

#define COMPUTE_TILE()                                                           \
  _Pragma("unroll") for (int ks = 0; ks < 8; ++ks) {                             \
    bf16x8 a[4];                                                                 \
    _Pragma("unroll") for (int rf = 0; rf < 4; ++rf) {                           \
      int row = rf * 16 + lm;                                                    \
      int off;                                                                   \
      if (ks < 3)      off = row * R1_STRIDE + (ks * 4 + hi) * 8;                \
      else if (ks < 6) off = R2_BASE + row * R1_STRIDE + ((ks - 3) * 4 + hi) * 8;\
      else             off = RE_BASE + row * RE_STRIDE + ((ks - 6) * 4 + hi) * 8;\
      a[rf] = *reinterpret_cast<const bf16x8*>(&As[off]);                        \
    }                                                                            \
    _Pragma("unroll") for (int rf = 0; rf < 4; ++rf)                             \
    _Pragma("unroll") for (int ct = 0; ct < 2; ++ct)                             \
        acc[rf][ct] = __builtin_amdgcn_mfma_f32_16x16x32_bf16(                   \
            a[rf], breg[ct][ks], acc[rf][ct], 0, 0, 0);                          \
  }

// PASS 0: column stats of y = XW, original edge order (rperm_ harmless)
__global__ __launch_bounds__(384, 3) void k_gstats(
    const unsigned short* __restrict__ nb, const unsigned short* __restrict__ eb,
    const unsigned short* __restrict__ Wt, const int* __restrict__ idx1,
    const int* __restrict__ idx2, float* __restrict__ colsum, float* __restrict__ colsumsq) {
  __shared__ unsigned short As[LDS_SHORTS];
  GEMM_PROLOGUE();
  float s1a[2] = {0.f, 0.f}, s2a[2] = {0.f, 0.f};

#define LOAD_TILE0(T)                                                            \
  {                                                                              \
    const int e0_ = (T) * 64;                                                    \
    _Pragma("unroll") for (int k = 0; k < 6; ++k) {                              \
      int i = tid + k * 384;                                                     \
      if (i < NCHUNK) {                                                          \
        const unsigned short* src;                                               \
        if (i < 768)       { int r = i / 12, c = i % 12;                         \
                             src = nb + (size_t)idx1[e0_ + rperm_(r)] * NF + c * 8; } \
        else if (i < 1536) { int ii = i - 768; int r = ii / 12, c = ii % 12;     \
                             src = nb + (size_t)idx2[e0_ + rperm_(r)] * NF + c * 8; } \
        else               { int ii = i - 1536; int r = ii >> 3, c = ii & 7;     \
                             src = eb + (size_t)(e0_ + rperm_(r)) * FE + c * 8; } \
        sv[k] = *reinterpret_cast<const uint4*>(src);                            \
      }                                                                          \
    }                                                                            \
  }

  int tile = blockIdx.x;
  if (tile < NTILES) LOAD_TILE0(tile);
  for (; tile < NTILES; tile += gridDim.x) {
    __syncthreads();
    WRITE_TILE();
    __syncthreads();
    int nt = tile + gridDim.x;
    if (nt < NTILES) LOAD_TILE0(nt);

    f32x4 acc[4][2];
#pragma unroll
    for (int rf = 0; rf < 4; ++rf)
#pragma unroll
      for (int ct = 0; ct < 2; ++ct) acc[rf][ct] = (f32x4)(0.f);
    COMPUTE_TILE();

#pragma unroll
    for (int ct = 0; ct < 2; ++ct)
#pragma unroll
      for (int rf = 0; rf < 4; ++rf)
#pragma unroll
        for (int j = 0; j < 4; ++j) {
          float y = acc[rf][ct][j];
          s1a[ct] += y;
          s2a[ct] += y * y;
        }
  }

#pragma unroll
  for (int ct = 0; ct < 2; ++ct) {
    float s1 = s1a[ct], s2 = s2a[ct];
    s1 += __shfl_xor(s1, 16); s2 += __shfl_xor(s2, 16);
    s1 += __shfl_xor(s1, 32); s2 += __shfl_xor(s2, 32);
    if (lane < 16) {
      atomicAdd(&colsum[base_c + ct * 16 + lane], s1);
      atomicAdd(&colsumsq[base_c + ct * 16 + lane], s2);
    }
  }
}

// PASS 1: sorted edges, row-permuted staging; in-register segmented scatter.
// Thread (hi) holds 16 consecutive sorted edges e0+hi*16+k for col mcol.
__global__ __launch_bounds__(384, 3) void k_gmsg2(
    const unsigned short* __restrict__ nb, const unsigned short* __restrict__ eb,
    const unsigned short* __restrict__ Wt, const int* __restrict__ perm,
    const int* __restrict__ i1s, const int* __restrict__ idx2,
    const float* __restrict__ a1, const float* __restrict__ b1f,
    float* __restrict__ sums) {
  __shared__ unsigned short As[LDS_SHORTS];
  __shared__ int nid[64];
  GEMM_PROLOGUE();
  float c0[2], c1[2];
#pragma unroll
  for (int ct = 0; ct < 2; ++ct) {
    c0[ct] = a1[base_c + ct * 16 + lm];
    c1[ct] = b1f[base_c + ct * 16 + lm];
  }

#define LOAD_TILE1(T)                                                            \
  {                                                                              \
    const int e0_ = (T) * 64;                                                    \
    _Pragma("unroll") for (int k = 0; k < 6; ++k) {                              \
      int i = tid + k * 384;                                                     \
      if (i < NCHUNK) {                                                          \
        const unsigned short* src;                                               \
        if (i < 768)       { int r = i / 12, c = i % 12;                         \
                             src = nb + (size_t)i1s[e0_ + rperm_(r)] * NF + c * 8; } \
        else if (i < 1536) { int ii = i - 768; int r = ii / 12, c = ii % 12;     \
                             int ep = perm[e0_ + rperm_(r)];                     \
                             src = nb + (size_t)idx2[ep] * NF + c * 8; }         \
        else               { int ii = i - 1536; int r = ii >> 3, c = ii & 7;     \
                             int ep = perm[e0_ + rperm_(r)];                     \
                             src = eb + (size_t)ep * FE + c * 8; }               \
        sv[k] = *reinterpret_cast<const uint4*>(src);                            \
      }                                                                          \
    }                                                                            \
  }

  int tile = blockIdx.x;
  if (tile < NTILES) LOAD_TILE1(tile);
  for (; tile < NTILES; tile += gridDim.x) {
    const int e0 = tile * 64;
    __syncthreads();  // (A) prev epilogue done (nid safe to overwrite)
    WRITE_TILE();
    if (tid < 64) nid[tid] = i1s[e0 + tid];
    __syncthreads();  // (B)
    int nt = tile + gridDim.x;
    if (nt < NTILES) LOAD_TILE1(nt);

    f32x4 acc[4][2];
#pragma unroll
    for (int rf = 0; rf < 4; ++rf)
#pragma unroll
      for (int ct = 0; ct < 2; ++ct) acc[rf][ct] = (f32x4)(0.f);
    COMPUTE_TILE();

    // in-register segmented scatter: edges e0+hi*16+0..15 in (rf,j) lex order
    const int mcol = w * 16 + lm;
    float run = 0.f;
    int curn = nid[hi * 16];
#pragma unroll
    for (int rf = 0; rf < 4; ++rf)
#pragma unroll
      for (int j = 0; j < 4; ++j) {
        int k = rf * 4 + j;
        float zg = acc[rf][0][j] * c0[0] + c1[0];
        float zc = acc[rf][1][j] * c0[1] + c1[1];
        run += sigmoidf_(zg) * softplusf_(zc);
        int nxt = (k < 15) ? nid[hi * 16 + k + 1] : -1;
        if (nxt != curn) {
          atomicAdd(&sums[(size_t)curn * NF + mcol], run);
          run = 0.f;
          curn = nxt;
        }
      }
  }
}

// ---------------- BN affine computation ----------------
__global__ void k_bn1(const float* __restrict__ colsum, const float* __restrict__ colsumsq,
                      const float* __restrict__ gamma1, const float* __restrict__ beta1,
                      float* __restrict__ a1, float* __restrict__ b1f) {
  int c = threadIdx.x;  // 192, our col space
  int o = col_perm(c);
  float my = colsum[c] * (1.f / N_EDGES);
  float v = colsumsq[c] * (1.f / N_EDGES) - my * my;
  float a = gamma1[o] * rsqrtf(v + BN_EPS);
  a1[c] = a;
  b1f[c] = beta1[o] - my * a;  // bias cancels against batch mean
}

__global__ void k_nodestats(const float* __restrict__ sums, const int* __restrict__ icounts,
                            float* __restrict__ colsum2, float* __restrict__ colsumsq2) {
  __shared__ float sh[2][2][96];
  int t = threadIdx.x;  // 192
  int c = t % 96, sub = t / 96;
  float s1 = 0.f, s2 = 0.f;
  int n0 = blockIdx.x * 256;
  for (int r = sub; r < 256; r += 2) {
    int n = n0 + r;
    if (n < N_NODES) {
      float v = sums[(size_t)n * NF + c] / fmaxf((float)icounts[n], 1.f);
      s1 += v; s2 += v * v;
    }
  }
  sh[0][sub][c] = s1; sh[1][sub][c] = s2;
  __syncthreads();
  if (sub == 0) {
    atomicAdd(&colsum2[c], s1 + sh[0][1][c]);
    atomicAdd(&colsumsq2[c], s2 + sh[1][1][c]);
  }
}

__global__ void k_bn2(const float* __restrict__ colsum2, const float* __restrict__ colsumsq2,
                      const float* __restrict__ gamma2, const float* __restrict__ beta2,
                      float* __restrict__ a2, float* __restrict__ b2f) {
  int c = threadIdx.x;
  if (c < 96) {
    float m = colsum2[c] * (1.f / N_NODES);
    float v = colsumsq2[c] * (1.f / N_NODES) - m * m;
    float a = gamma2[c] * rsqrtf(v + BN_EPS);
    a2[c] = a;
    b2f[c] = beta2[c] - m * a;
  }
}

__global__ void k_final(const float* __restrict__ node, const float* __restrict__ sums,
                        const int* __restrict__ icounts, const float* __restrict__ a2,
                        const float* __restrict__ b2f, float* __restrict__ out) {
  int stride = gridDim.x * blockDim.x;
  for (int i = blockIdx.x * blockDim.x + threadIdx.x; i < N_NODES * NF / 4; i += stride) {
    int n = i / 24, c4 = (i % 24) * 4;
    float inv = 1.f / fmaxf((float)icounts[n], 1.f);
    float4 s = reinterpret_cast<const float4*>(sums)[i];
    float4 nf = reinterpret_cast<const float4*>(node)[i];
    float4 o;
    o.x = softplusf_(nf.x + s.x * inv * a2[c4 + 0] + b2f[c4 + 0]);
    o.y = softplusf_(nf.y + s.y * inv * a2[c4 + 1] + b2f[c4 + 1]);
    o.z = softplusf_(nf.z + s.z * inv * a2[c4 + 2] + b2f[c4 + 2]);
    o.w = softplusf_(nf.w + s.w * inv * a2[c4 + 3] + b2f[c4 + 3]);
    reinterpret_cast<float4*>(out)[i] = o;
  }
}

extern "C" void kernel_launch(void* const* d_in, const int* in_sizes, int n_in,
                              void* d_out, int out_size, void* d_ws, size_t ws_size,
                              hipStream_t stream) {
  const float* node = (const float*)d_in[0];
  const float* edge = (const float*)d_in[1];
  const float* W = (const float*)d_in[2];
  const float* gamma1 = (const float*)d_in[4];
  const float* beta1 = (const float*)d_in[5];
  const float* gamma2 = (const float*)d_in[6];
  const float* beta2 = (const float*)d_in[7];
  const int* idx1 = (const int*)d_in[8];
  const int* idx2 = (const int*)d_in[9];
  float* out = (float*)d_out;

  char* ws = (char*)d_ws;
  unsigned short* nb = (unsigned short*)(ws);               //   9,600,000
  unsigned short* eb = (unsigned short*)(ws + 9600000);     // 102,400,000
  unsigned short* Wt = (unsigned short*)(ws + 112000000);   //      98,304
  float* sums = (float*)(ws + 112098304);                   //  19,200,000
  float* stats = (float*)(ws + 131298304);                  //       8,192
  int* icounts = (int*)(ws + 131306496);                    //     200,000
  int* perm = (int*)(ws + 131506496);                       //   3,200,000
  int* i1s = (int*)(ws + 134706496);                        //   3,200,000
  // total 137,906,496 bytes

  // overlay at head of sums (used only before k_gmsg2, re-zeroed after)
  int* offsets = (int*)(ws + 112098304);        // 50000 ints
  int* cursor = offsets + 50048;                // 50000 ints

  float* colsum1 = stats;          // 192
  float* colsumsq1 = stats + 192;  // 192
  float* colsum2 = stats + 384;    // 96
  float* colsumsq2 = stats + 480;  // 96
  float* a1 = stats + 576;         // 192
  float* b1f = stats + 768;        // 192
  float* a2 = stats + 960;         // 96
  float* b2f = stats + 1056;       // 96
  int* bsum = (int*)(ws + 131303424);  // 128 ints
  int* boff = (int*)(ws + 131303936);  // 128 ints

  // zero sums (incl. offsets/cursor overlay) + stats + icounts
  (void)hipMemsetAsync(ws + 112098304, 0, 19200000 + 8192 + 200000, stream);

  k_cvt<<<2048, 256, 0, stream>>>(node, nb, N_NODES * NF / 4);
  k_cvt<<<2048, 256, 0, stream>>>(edge, eb, N_EDGES * FE / 4);
  k_cvt_w<<<DOUT * DIN / 256, 256, 0, stream>>>(W, Wt);
  k_hist<<<1024, 256, 0, stream>>>(idx1, icounts);
  k_scanA<<<SCAN_NB, SCAN_B, 0, stream>>>(icounts, offsets, bsum);
  k_scanB<<<1, 128, 0, stream>>>(bsum, boff);
  k_scanC<<<SCAN_NB, SCAN_B, 0, stream>>>(offsets, boff);
  k_perm<<<1024, 256, 0, stream>>>(idx1, offsets, cursor, perm, i1s);

  k_gstats<<<1024, 384, 0, stream>>>(nb, eb, Wt, idx1, idx2, colsum1, colsumsq1);
  k_bn1<<<1, 192, 0, stream>>>(colsum1, colsumsq1, gamma1, beta1, a1, b1f);

  // re-zero the overlay region before atomic accumulation into sums
  (void)hipMemsetAsync(ws + 112098304, 0, 524288, stream);

  k_gmsg2<<<1024, 384, 0, stream>>>(nb, eb, Wt, perm, i1s, idx2, a1, b1f, sums);

  k_nodestats<<<(N_NODES + 255) / 256, 192, 0, stream>>>(sums, icounts, colsum2, colsumsq2);
  k_bn2<<<1, 128, 0, stream>>>(colsum2, colsumsq2, gamma2, beta2, a2, b2f);
  k_final<<<2048, 256, 0, stream>>>(node, sums, icounts, a2, b2f, out);
}